// Round 4
// baseline (312.277 us; speedup 1.0000x reference)
//
#include <hip/hip_runtime.h>

#define NB 16
#define NN 2048
#define DH 64
#define NSEL 228     // int(30 * ln(2048))
#define KS 8         // attention key-split chunks
#define CHUNK (NN / KS)
#define RS 8         // rowstat key-split

// ---------------------------------------------------------------------------
// Kernel A: partial row stats of S = Q K^T over a key chunk of 256.
// 128q x 128k block tile, 8x8 per-thread acc, d staged in halves of 32.
// Register vectors split across tile halves ([tx*4] and [64+tx*4]) so LDS
// reads are 16B-stride (2-way aliasing = free) instead of 32B (4-way).
// Row mapping is adjusted at the output write (max/sum are k-perm-invariant).
// ---------------------------------------------------------------------------
__global__ __launch_bounds__(256, 5) void rowstat_kernel(const float* __restrict__ Q,
                                                         const float* __restrict__ K,
                                                         float* __restrict__ Mmax,
                                                         float* __restrict__ Msum) {
  __shared__ float Qt[32][128];  // [d][q]
  __shared__ float Kt[32][128];  // [d][k]
  const int b = blockIdx.y;
  const int cz = blockIdx.z;
  const int qbase = blockIdx.x * 128;
  const int tid = threadIdx.x;
  const int r = tid & 127;          // staging row
  const int h16 = (tid >> 7) * 16;  // staging d-offset (0 or 16)
  const int ty = tid >> 4;          // 0..15 -> q quartet (per half)
  const int tx = tid & 15;          // 0..15 -> k quartet (per half)
  const float* Qb = Q + ((size_t)b * NN + qbase) * DH;
  const float* Kb = K + ((size_t)b * NN + cz * (NN / RS)) * DH;

  float rmax[8], rsum[8];
  #pragma unroll
  for (int a = 0; a < 8; ++a) { rmax[a] = -3.0e38f; rsum[a] = 0.f; }

  for (int kt = 0; kt < NN / RS / 128; ++kt) {
    float acc[8][8];
    #pragma unroll
    for (int a = 0; a < 8; ++a)
      #pragma unroll
      for (int c = 0; c < 8; ++c) acc[a][c] = 0.f;

    #pragma unroll
    for (int half = 0; half < 2; ++half) {
      const int d0 = half * 32;
      __syncthreads();
      {
        const float* qs = Qb + r * DH + d0 + h16;
        const float* ks = Kb + ((size_t)(kt * 128 + r)) * DH + d0 + h16;
        #pragma unroll
        for (int f = 0; f < 4; ++f) {
          float4 v = *reinterpret_cast<const float4*>(qs + f * 4);
          Qt[h16 + f * 4 + 0][r] = v.x;
          Qt[h16 + f * 4 + 1][r] = v.y;
          Qt[h16 + f * 4 + 2][r] = v.z;
          Qt[h16 + f * 4 + 3][r] = v.w;
          float4 w = *reinterpret_cast<const float4*>(ks + f * 4);
          Kt[h16 + f * 4 + 0][r] = w.x;
          Kt[h16 + f * 4 + 1][r] = w.y;
          Kt[h16 + f * 4 + 2][r] = w.z;
          Kt[h16 + f * 4 + 3][r] = w.w;
        }
      }
      __syncthreads();

      #pragma unroll 2
      for (int d = 0; d < 32; ++d) {
        float qv[8], kv[8];
        // split-half reads: 16B stride within each -> conflict-free
        *reinterpret_cast<float4*>(qv) =
            *reinterpret_cast<const float4*>(&Qt[d][ty * 4]);
        *reinterpret_cast<float4*>(qv + 4) =
            *reinterpret_cast<const float4*>(&Qt[d][64 + ty * 4]);
        *reinterpret_cast<float4*>(kv) =
            *reinterpret_cast<const float4*>(&Kt[d][tx * 4]);
        *reinterpret_cast<float4*>(kv + 4) =
            *reinterpret_cast<const float4*>(&Kt[d][64 + tx * 4]);
        #pragma unroll
        for (int a = 0; a < 8; ++a)
          #pragma unroll
          for (int c = 0; c < 8; ++c) acc[a][c] = fmaf(qv[a], kv[c], acc[a][c]);
      }
    }

    #pragma unroll
    for (int a = 0; a < 8; ++a)
      #pragma unroll
      for (int c = 0; c < 8; ++c) {
        rmax[a] = fmaxf(rmax[a], acc[a][c]);
        rsum[a] += acc[a][c];
      }
  }

  #pragma unroll
  for (int off = 1; off < 16; off <<= 1) {
    #pragma unroll
    for (int a = 0; a < 8; ++a) {
      rmax[a] = fmaxf(rmax[a], __shfl_xor(rmax[a], off));
      rsum[a] += __shfl_xor(rsum[a], off);
    }
  }
  if (tx == 0) {
    #pragma unroll
    for (int a = 0; a < 8; ++a) {
      // q-local = half*64 + ty*4 + (a&3)
      const int qlocal = (a >> 2) * 64 + ty * 4 + (a & 3);
      const size_t idx = ((size_t)cz * NB + b) * NN + qbase + qlocal;
      Mmax[idx] = rmax[a];
      Msum[idx] = rsum[a];
    }
  }
}

// ---------------------------------------------------------------------------
// Kernel B: per-batch top-228 (set semantics, ties index-ascending).
// ---------------------------------------------------------------------------
__global__ __launch_bounds__(256) void select_kernel(const float* __restrict__ Mmax,
                                                     const float* __restrict__ Msum,
                                                     int* __restrict__ Isel) {
  __shared__ int red[4];
  const int b = blockIdx.x;
  const int tid = threadIdx.x;
  const int lane = tid & 63;
  const int wid = tid >> 6;
  const int base = tid * 8;

  unsigned int kreg[8];
  #pragma unroll
  for (int f = 0; f < 8; ++f) {
    const int i = base + f;
    float mv = -3.0e38f, sv = 0.f;
    #pragma unroll
    for (int cz = 0; cz < RS; ++cz) {
      const size_t idx = ((size_t)cz * NB + b) * NN + i;
      mv = fmaxf(mv, Mmax[idx]);
      sv += Msum[idx];
    }
    const float M = mv - sv * (1.0f / NN);
    const unsigned int uu = __float_as_uint(M);
    kreg[f] = (uu & 0x80000000u) ? ~uu : (uu | 0x80000000u);
  }

  unsigned int v = 0u;
  for (int bit = 31; bit >= 0; --bit) {
    const unsigned int cand = v | (1u << bit);
    int c = 0;
    #pragma unroll
    for (int f = 0; f < 8; ++f) c += (kreg[f] >= cand) ? 1 : 0;
    #pragma unroll
    for (int off = 1; off < 64; off <<= 1) c += __shfl_xor(c, off);
    if (lane == 0) red[wid] = c;
    __syncthreads();
    const int total = red[0] + red[1] + red[2] + red[3];
    if (total >= NSEL) v = cand;
    __syncthreads();
  }

  int flg[8];
  int cnt = 0;
  #pragma unroll
  for (int f = 0; f < 8; ++f) { flg[f] = (kreg[f] > v) ? 1 : 0; cnt += flg[f]; }
  int scan = cnt;
  #pragma unroll
  for (int off = 1; off < 64; off <<= 1) {
    const int n = __shfl_up(scan, off);
    if (lane >= off) scan += n;
  }
  if (lane == 63) red[wid] = scan;
  __syncthreads();
  int wbase = 0;
  for (int w = 0; w < wid; ++w) wbase += red[w];
  const int cg = red[0] + red[1] + red[2] + red[3];
  int pos = wbase + scan - cnt;
  #pragma unroll
  for (int f = 0; f < 8; ++f)
    if (flg[f]) { Isel[b * NSEL + pos] = base + f; ++pos; }
  __syncthreads();

  const int need = NSEL - cg;
  cnt = 0;
  #pragma unroll
  for (int f = 0; f < 8; ++f) { flg[f] = (kreg[f] == v) ? 1 : 0; cnt += flg[f]; }
  scan = cnt;
  #pragma unroll
  for (int off = 1; off < 64; off <<= 1) {
    const int n = __shfl_up(scan, off);
    if (lane >= off) scan += n;
  }
  if (lane == 63) red[wid] = scan;
  __syncthreads();
  wbase = 0;
  for (int w = 0; w < wid; ++w) wbase += red[w];
  pos = wbase + scan - cnt;
  #pragma unroll
  for (int f = 0; f < 8; ++f)
    if (flg[f]) {
      if (pos < need) Isel[b * NSEL + cg + pos] = base + f;
      ++pos;
    }
}

// ---------------------------------------------------------------------------
// Kernel C: fill out[b][i][:] = mean_d V[b][i][:]
// ---------------------------------------------------------------------------
__global__ __launch_bounds__(256) void fill_kernel(const float* __restrict__ V,
                                                   float* __restrict__ out) {
  const size_t row = (size_t)blockIdx.x * 4 + (threadIdx.x >> 6);
  const int lane = threadIdx.x & 63;
  float x = V[row * DH + lane];
  #pragma unroll
  for (int off = 1; off < 64; off <<= 1) x += __shfl_xor(x, off);
  out[row * DH + lane] = x * (1.0f / DH);
}

// ---------------------------------------------------------------------------
// Kernel D: flash partials, register-tiled.
// Block: 32 selected queries x 256-key chunk, 64-key subtiles.
// scores GEMM (4q x 2k /thread) -> shfl row-max -> exp -> P via LDS
// (Pt rows 36 floats: 16B-aligned b128, spread banks) -> PV GEMM (4q x 2d).
// ---------------------------------------------------------------------------
__global__ __launch_bounds__(256) void attn_part_kernel(const float* __restrict__ Q,
                                                        const float* __restrict__ K,
                                                        const float* __restrict__ V,
                                                        const int* __restrict__ Isel,
                                                        float* __restrict__ Pm,
                                                        float* __restrict__ Pl,
                                                        float* __restrict__ Po) {
  __shared__ float Qt[64][32];   // [d][q]
  __shared__ float Kt[64][64];   // [d][k]
  __shared__ float Vs[64][64];   // [k][d]
  __shared__ float Pt[64][36];   // [k][q] padded to 144B rows
  const int b = blockIdx.z;
  const int kc = blockIdx.y;
  const int g = blockIdx.x;
  const int tid = threadIdx.x;
  const int wq = tid >> 5;  // 0..7 -> q quartet
  const int kx = tid & 31;  // scores: k pair; PV: d pair

  // stage gathered Q^T once
  if (tid < 128) {
    const int rr = tid >> 2;
    const int dblk = (tid & 3) * 16;
    const int lq = g * 32 + rr;
    const int qidx = (lq < NSEL) ? Isel[b * NSEL + lq] : 0;
    const float* qs = Q + ((size_t)b * NN + qidx) * DH + dblk;
    #pragma unroll
    for (int f = 0; f < 4; ++f) {
      float4 v = *reinterpret_cast<const float4*>(qs + f * 4);
      Qt[dblk + f * 4 + 0][rr] = v.x;
      Qt[dblk + f * 4 + 1][rr] = v.y;
      Qt[dblk + f * 4 + 2][rr] = v.z;
      Qt[dblk + f * 4 + 3][rr] = v.w;
    }
  }

  const float* Kb = K + ((size_t)b * NN + kc * CHUNK) * DH;
  const float* Vb = V + ((size_t)b * NN + kc * CHUNK) * DH;

  float m[4], lp[4], o[4][2];
  #pragma unroll
  for (int a = 0; a < 4; ++a) {
    m[a] = -3.0e38f; lp[a] = 0.f; o[a][0] = 0.f; o[a][1] = 0.f;
  }

  for (int st = 0; st < CHUNK / 64; ++st) {
    __syncthreads();  // previous Pt/Vs/Kt consumed
    {
      // Kt transposed
      const int rr = tid & 63;
      const int dblk = (tid >> 6) * 16;
      const float* ks = Kb + ((size_t)(st * 64 + rr)) * DH + dblk;
      #pragma unroll
      for (int f = 0; f < 4; ++f) {
        float4 v = *reinterpret_cast<const float4*>(ks + f * 4);
        Kt[dblk + f * 4 + 0][rr] = v.x;
        Kt[dblk + f * 4 + 1][rr] = v.y;
        Kt[dblk + f * 4 + 2][rr] = v.z;
        Kt[dblk + f * 4 + 3][rr] = v.w;
      }
      // Vs flat copy (global rows contiguous == LDS layout)
      const float* vsrc = Vb + (size_t)st * 64 * DH;
      float* vdst = &Vs[0][0];
      #pragma unroll
      for (int it = 0; it < 4; ++it) {
        const int fo = (it * 256 + tid) * 4;
        *reinterpret_cast<float4*>(vdst + fo) =
            *reinterpret_cast<const float4*>(vsrc + fo);
      }
    }
    __syncthreads();

    // scores
    float sc[4][2];
    #pragma unroll
    for (int a = 0; a < 4; ++a) { sc[a][0] = 0.f; sc[a][1] = 0.f; }
    #pragma unroll 4
    for (int d = 0; d < 64; ++d) {
      float qv[4];
      *reinterpret_cast<float4*>(qv) =
          *reinterpret_cast<const float4*>(&Qt[d][wq * 4]);
      const float2 kv = *reinterpret_cast<const float2*>(&Kt[d][kx * 2]);
      #pragma unroll
      for (int a = 0; a < 4; ++a) {
        sc[a][0] = fmaf(qv[a], kv.x, sc[a][0]);
        sc[a][1] = fmaf(qv[a], kv.y, sc[a][1]);
      }
    }
    #pragma unroll
    for (int a = 0; a < 4; ++a) { sc[a][0] *= 0.125f; sc[a][1] *= 0.125f; }

    // row max over the 32 kx lanes
    float tm[4];
    #pragma unroll
    for (int a = 0; a < 4; ++a) tm[a] = fmaxf(sc[a][0], sc[a][1]);
    #pragma unroll
    for (int off = 1; off < 32; off <<= 1) {
      #pragma unroll
      for (int a = 0; a < 4; ++a) tm[a] = fmaxf(tm[a], __shfl_xor(tm[a], off));
    }

    // online update + exp
    float w0[4], w1[4];
    #pragma unroll
    for (int a = 0; a < 4; ++a) {
      const float mn = fmaxf(m[a], tm[a]);
      const float scale = __expf(m[a] - mn);
      m[a] = mn;
      lp[a] *= scale;
      o[a][0] *= scale;
      o[a][1] *= scale;
      w0[a] = __expf(sc[a][0] - mn);
      w1[a] = __expf(sc[a][1] - mn);
      lp[a] += w0[a] + w1[a];
    }
    *reinterpret_cast<float4*>(&Pt[kx * 2][wq * 4]) =
        make_float4(w0[0], w0[1], w0[2], w0[3]);
    *reinterpret_cast<float4*>(&Pt[kx * 2 + 1][wq * 4]) =
        make_float4(w1[0], w1[1], w1[2], w1[3]);
    __syncthreads();

    // PV
    #pragma unroll 4
    for (int k = 0; k < 64; ++k) {
      float pv[4];
      *reinterpret_cast<float4*>(pv) =
          *reinterpret_cast<const float4*>(&Pt[k][wq * 4]);
      const float2 vv = *reinterpret_cast<const float2*>(&Vs[k][kx * 2]);
      #pragma unroll
      for (int a = 0; a < 4; ++a) {
        o[a][0] = fmaf(pv[a], vv.x, o[a][0]);
        o[a][1] = fmaf(pv[a], vv.y, o[a][1]);
      }
    }
  }

  // total l across kx lanes
  #pragma unroll
  for (int off = 1; off < 32; off <<= 1) {
    #pragma unroll
    for (int a = 0; a < 4; ++a) lp[a] += __shfl_xor(lp[a], off);
  }

  #pragma unroll
  for (int a = 0; a < 4; ++a) {
    const int lq = g * 32 + wq * 4 + a;
    if (lq < NSEL) {
      const size_t row = ((size_t)b * NSEL + lq) * KS + kc;
      if (kx == 0) { Pm[row] = m[a]; Pl[row] = lp[a]; }
      *reinterpret_cast<float2*>(Po + row * 64 + kx * 2) =
          make_float2(o[a][0], o[a][1]);
    }
  }
}

// ---------------------------------------------------------------------------
// Kernel E: merge the KS partials per selected row; write final output.
// ---------------------------------------------------------------------------
__global__ __launch_bounds__(256) void combine_kernel(const int* __restrict__ Isel,
                                                      const float* __restrict__ Pm,
                                                      const float* __restrict__ Pl,
                                                      const float* __restrict__ Po,
                                                      float* __restrict__ out) {
  const int r = blockIdx.x * 4 + (threadIdx.x >> 6);
  if (r >= NB * NSEL) return;
  const int lane = threadIdx.x & 63;
  const int b = r / NSEL;
  const int qidx = Isel[r];
  const size_t base = (size_t)r * KS;

  float pm[KS];
  float gm = -3.0e38f;
  #pragma unroll
  for (int c = 0; c < KS; ++c) { pm[c] = Pm[base + c]; gm = fmaxf(gm, pm[c]); }
  float L = 0.f, od = 0.f;
  #pragma unroll
  for (int c = 0; c < KS; ++c) {
    const float e = __expf(pm[c] - gm);
    L += Pl[base + c] * e;
    od += Po[(base + c) * 64 + lane] * e;
  }
  out[((size_t)b * NN + qidx) * DH + lane] = od / L;
}

// ---------------------------------------------------------------------------
extern "C" void kernel_launch(void* const* d_in, const int* in_sizes, int n_in,
                              void* d_out, int out_size, void* d_ws, size_t ws_size,
                              hipStream_t stream) {
  const float* Q = (const float*)d_in[0];
  const float* K = (const float*)d_in[1];
  const float* V = (const float*)d_in[2];
  // d_in[3] (seed) unused: U == n -> full permutation; max/mean are
  // permutation-invariant, so M equals rowmax - rowmean of the full QK^T.
  float* out = (float*)d_out;

  float* Mmax = (float*)d_ws;                        // RS*NB*NN
  float* Msum = Mmax + (size_t)RS * NB * NN;         // RS*NB*NN
  int* Isel = (int*)(Msum + (size_t)RS * NB * NN);   // NB*NSEL
  float* Pm = (float*)(Isel + NB * NSEL);            // NB*NSEL*KS
  float* Pl = Pm + (size_t)NB * NSEL * KS;           // NB*NSEL*KS
  float* Po = Pl + (size_t)NB * NSEL * KS;           // NB*NSEL*KS*64

  rowstat_kernel<<<dim3(NN / 128, NB, RS), 256, 0, stream>>>(Q, K, Mmax, Msum);
  select_kernel<<<dim3(NB), 256, 0, stream>>>(Mmax, Msum, Isel);
  fill_kernel<<<dim3(NB * NN / 4), 256, 0, stream>>>(V, out);
  attn_part_kernel<<<dim3(8, KS, NB), 256, 0, stream>>>(Q, K, V, Isel, Pm, Pl, Po);
  combine_kernel<<<dim3((NB * NSEL + 3) / 4), 256, 0, stream>>>(Isel, Pm, Pl, Po, out);
}

// Round 5
// 254.377 us; speedup vs baseline: 1.2276x; 1.2276x over previous
//
#include <hip/hip_runtime.h>

#define NB 16
#define NN 2048
#define DH 64
#define NSEL 228     // int(30 * ln(2048))
#define KS 8         // attention key-split chunks
#define CHUNK (NN / KS)
#define RS 8         // rowstat key-split

// ---------------------------------------------------------------------------
// Kernel A: partial row stats of S = Q K^T over a key chunk of 256.
// 128q x 128k block tile, 8x8 per-thread acc, d staged in halves of 32.
// LDS reads split across tile halves ([tx*4], [64+tx*4]): 16B stride = 2-way
// aliasing = free. launch_bounds(256,2): cap 256 VGPR -- the 8x8 fp32 acc
// (64 regs) must NOT spill (round-4 lesson: (256,5) forced 48 VGPR -> 186 MB
// scratch writes). ~105 VGPR -> 4 waves/SIMD via the 128-step anyway.
// ---------------------------------------------------------------------------
__global__ __launch_bounds__(256, 2) void rowstat_kernel(const float* __restrict__ Q,
                                                         const float* __restrict__ K,
                                                         float* __restrict__ Mmax,
                                                         float* __restrict__ Msum) {
  __shared__ float Qt[32][128];  // [d][q]
  __shared__ float Kt[32][128];  // [d][k]
  const int b = blockIdx.y;
  const int cz = blockIdx.z;
  const int qbase = blockIdx.x * 128;
  const int tid = threadIdx.x;
  const int r = tid & 127;          // staging row
  const int h16 = (tid >> 7) * 16;  // staging d-offset (0 or 16)
  const int ty = tid >> 4;          // 0..15 -> q quartet (per half)
  const int tx = tid & 15;          // 0..15 -> k quartet (per half)
  const float* Qb = Q + ((size_t)b * NN + qbase) * DH;
  const float* Kb = K + ((size_t)b * NN + cz * (NN / RS)) * DH;

  float rmax[8], rsum[8];
  #pragma unroll
  for (int a = 0; a < 8; ++a) { rmax[a] = -3.0e38f; rsum[a] = 0.f; }

  for (int kt = 0; kt < NN / RS / 128; ++kt) {
    float acc[8][8];
    #pragma unroll
    for (int a = 0; a < 8; ++a)
      #pragma unroll
      for (int c = 0; c < 8; ++c) acc[a][c] = 0.f;

    #pragma unroll
    for (int half = 0; half < 2; ++half) {
      const int d0 = half * 32;
      __syncthreads();
      {
        const float* qs = Qb + r * DH + d0 + h16;
        const float* ks = Kb + ((size_t)(kt * 128 + r)) * DH + d0 + h16;
        #pragma unroll
        for (int f = 0; f < 4; ++f) {
          float4 v = *reinterpret_cast<const float4*>(qs + f * 4);
          Qt[h16 + f * 4 + 0][r] = v.x;
          Qt[h16 + f * 4 + 1][r] = v.y;
          Qt[h16 + f * 4 + 2][r] = v.z;
          Qt[h16 + f * 4 + 3][r] = v.w;
          float4 w = *reinterpret_cast<const float4*>(ks + f * 4);
          Kt[h16 + f * 4 + 0][r] = w.x;
          Kt[h16 + f * 4 + 1][r] = w.y;
          Kt[h16 + f * 4 + 2][r] = w.z;
          Kt[h16 + f * 4 + 3][r] = w.w;
        }
      }
      __syncthreads();

      #pragma unroll 2
      for (int d = 0; d < 32; ++d) {
        float qv[8], kv[8];
        *reinterpret_cast<float4*>(qv) =
            *reinterpret_cast<const float4*>(&Qt[d][ty * 4]);
        *reinterpret_cast<float4*>(qv + 4) =
            *reinterpret_cast<const float4*>(&Qt[d][64 + ty * 4]);
        *reinterpret_cast<float4*>(kv) =
            *reinterpret_cast<const float4*>(&Kt[d][tx * 4]);
        *reinterpret_cast<float4*>(kv + 4) =
            *reinterpret_cast<const float4*>(&Kt[d][64 + tx * 4]);
        #pragma unroll
        for (int a = 0; a < 8; ++a)
          #pragma unroll
          for (int c = 0; c < 8; ++c) acc[a][c] = fmaf(qv[a], kv[c], acc[a][c]);
      }
    }

    #pragma unroll
    for (int a = 0; a < 8; ++a)
      #pragma unroll
      for (int c = 0; c < 8; ++c) {
        rmax[a] = fmaxf(rmax[a], acc[a][c]);
        rsum[a] += acc[a][c];
      }
  }

  #pragma unroll
  for (int off = 1; off < 16; off <<= 1) {
    #pragma unroll
    for (int a = 0; a < 8; ++a) {
      rmax[a] = fmaxf(rmax[a], __shfl_xor(rmax[a], off));
      rsum[a] += __shfl_xor(rsum[a], off);
    }
  }
  if (tx == 0) {
    #pragma unroll
    for (int a = 0; a < 8; ++a) {
      // q-local = half*64 + ty*4 + (a&3)
      const int qlocal = (a >> 2) * 64 + ty * 4 + (a & 3);
      const size_t idx = ((size_t)cz * NB + b) * NN + qbase + qlocal;
      Mmax[idx] = rmax[a];
      Msum[idx] = rsum[a];
    }
  }
}

// ---------------------------------------------------------------------------
// Kernel B: per-batch top-228 (set semantics, ties index-ascending).
// ---------------------------------------------------------------------------
__global__ __launch_bounds__(256) void select_kernel(const float* __restrict__ Mmax,
                                                     const float* __restrict__ Msum,
                                                     int* __restrict__ Isel) {
  __shared__ int red[4];
  const int b = blockIdx.x;
  const int tid = threadIdx.x;
  const int lane = tid & 63;
  const int wid = tid >> 6;
  const int base = tid * 8;

  unsigned int kreg[8];
  #pragma unroll
  for (int f = 0; f < 8; ++f) {
    const int i = base + f;
    float mv = -3.0e38f, sv = 0.f;
    #pragma unroll
    for (int cz = 0; cz < RS; ++cz) {
      const size_t idx = ((size_t)cz * NB + b) * NN + i;
      mv = fmaxf(mv, Mmax[idx]);
      sv += Msum[idx];
    }
    const float M = mv - sv * (1.0f / NN);
    const unsigned int uu = __float_as_uint(M);
    kreg[f] = (uu & 0x80000000u) ? ~uu : (uu | 0x80000000u);
  }

  unsigned int v = 0u;
  for (int bit = 31; bit >= 0; --bit) {
    const unsigned int cand = v | (1u << bit);
    int c = 0;
    #pragma unroll
    for (int f = 0; f < 8; ++f) c += (kreg[f] >= cand) ? 1 : 0;
    #pragma unroll
    for (int off = 1; off < 64; off <<= 1) c += __shfl_xor(c, off);
    if (lane == 0) red[wid] = c;
    __syncthreads();
    const int total = red[0] + red[1] + red[2] + red[3];
    if (total >= NSEL) v = cand;
    __syncthreads();
  }

  int flg[8];
  int cnt = 0;
  #pragma unroll
  for (int f = 0; f < 8; ++f) { flg[f] = (kreg[f] > v) ? 1 : 0; cnt += flg[f]; }
  int scan = cnt;
  #pragma unroll
  for (int off = 1; off < 64; off <<= 1) {
    const int n = __shfl_up(scan, off);
    if (lane >= off) scan += n;
  }
  if (lane == 63) red[wid] = scan;
  __syncthreads();
  int wbase = 0;
  for (int w = 0; w < wid; ++w) wbase += red[w];
  const int cg = red[0] + red[1] + red[2] + red[3];
  int pos = wbase + scan - cnt;
  #pragma unroll
  for (int f = 0; f < 8; ++f)
    if (flg[f]) { Isel[b * NSEL + pos] = base + f; ++pos; }
  __syncthreads();

  const int need = NSEL - cg;
  cnt = 0;
  #pragma unroll
  for (int f = 0; f < 8; ++f) { flg[f] = (kreg[f] == v) ? 1 : 0; cnt += flg[f]; }
  scan = cnt;
  #pragma unroll
  for (int off = 1; off < 64; off <<= 1) {
    const int n = __shfl_up(scan, off);
    if (lane >= off) scan += n;
  }
  if (lane == 63) red[wid] = scan;
  __syncthreads();
  wbase = 0;
  for (int w = 0; w < wid; ++w) wbase += red[w];
  pos = wbase + scan - cnt;
  #pragma unroll
  for (int f = 0; f < 8; ++f)
    if (flg[f]) {
      if (pos < need) Isel[b * NSEL + cg + pos] = base + f;
      ++pos;
    }
}

// ---------------------------------------------------------------------------
// Kernel C: fill out[b][i][:] = mean_d V[b][i][:]
// ---------------------------------------------------------------------------
__global__ __launch_bounds__(256) void fill_kernel(const float* __restrict__ V,
                                                   float* __restrict__ out) {
  const size_t row = (size_t)blockIdx.x * 4 + (threadIdx.x >> 6);
  const int lane = threadIdx.x & 63;
  float x = V[row * DH + lane];
  #pragma unroll
  for (int off = 1; off < 64; off <<= 1) x += __shfl_xor(x, off);
  out[row * DH + lane] = x * (1.0f / DH);
}

// ---------------------------------------------------------------------------
// Kernel D: flash partials, register-tiled.
// Block: 32 selected queries x 256-key chunk, 64-key subtiles.
// scores GEMM (4q x 2k /thread) -> shfl row-max -> exp -> P via LDS
// (Pt rows 36 floats: 16B-aligned b128, spread banks) -> PV GEMM (4q x 2d).
// ---------------------------------------------------------------------------
__global__ __launch_bounds__(256) void attn_part_kernel(const float* __restrict__ Q,
                                                        const float* __restrict__ K,
                                                        const float* __restrict__ V,
                                                        const int* __restrict__ Isel,
                                                        float* __restrict__ Pm,
                                                        float* __restrict__ Pl,
                                                        float* __restrict__ Po) {
  __shared__ float Qt[64][32];   // [d][q]
  __shared__ float Kt[64][64];   // [d][k]
  __shared__ float Vs[64][64];   // [k][d]
  __shared__ float Pt[64][36];   // [k][q] padded to 144B rows
  const int b = blockIdx.z;
  const int kc = blockIdx.y;
  const int g = blockIdx.x;
  const int tid = threadIdx.x;
  const int wq = tid >> 5;  // 0..7 -> q quartet
  const int kx = tid & 31;  // scores: k pair; PV: d pair

  // stage gathered Q^T once
  if (tid < 128) {
    const int rr = tid >> 2;
    const int dblk = (tid & 3) * 16;
    const int lq = g * 32 + rr;
    const int qidx = (lq < NSEL) ? Isel[b * NSEL + lq] : 0;
    const float* qs = Q + ((size_t)b * NN + qidx) * DH + dblk;
    #pragma unroll
    for (int f = 0; f < 4; ++f) {
      float4 v = *reinterpret_cast<const float4*>(qs + f * 4);
      Qt[dblk + f * 4 + 0][rr] = v.x;
      Qt[dblk + f * 4 + 1][rr] = v.y;
      Qt[dblk + f * 4 + 2][rr] = v.z;
      Qt[dblk + f * 4 + 3][rr] = v.w;
    }
  }

  const float* Kb = K + ((size_t)b * NN + kc * CHUNK) * DH;
  const float* Vb = V + ((size_t)b * NN + kc * CHUNK) * DH;

  float m[4], lp[4], o[4][2];
  #pragma unroll
  for (int a = 0; a < 4; ++a) {
    m[a] = -3.0e38f; lp[a] = 0.f; o[a][0] = 0.f; o[a][1] = 0.f;
  }

  for (int st = 0; st < CHUNK / 64; ++st) {
    __syncthreads();  // previous Pt/Vs/Kt consumed
    {
      // Kt transposed
      const int rr = tid & 63;
      const int dblk = (tid >> 6) * 16;
      const float* ks = Kb + ((size_t)(st * 64 + rr)) * DH + dblk;
      #pragma unroll
      for (int f = 0; f < 4; ++f) {
        float4 v = *reinterpret_cast<const float4*>(ks + f * 4);
        Kt[dblk + f * 4 + 0][rr] = v.x;
        Kt[dblk + f * 4 + 1][rr] = v.y;
        Kt[dblk + f * 4 + 2][rr] = v.z;
        Kt[dblk + f * 4 + 3][rr] = v.w;
      }
      // Vs flat copy (global rows contiguous == LDS layout)
      const float* vsrc = Vb + (size_t)st * 64 * DH;
      float* vdst = &Vs[0][0];
      #pragma unroll
      for (int it = 0; it < 4; ++it) {
        const int fo = (it * 256 + tid) * 4;
        *reinterpret_cast<float4*>(vdst + fo) =
            *reinterpret_cast<const float4*>(vsrc + fo);
      }
    }
    __syncthreads();

    // scores
    float sc[4][2];
    #pragma unroll
    for (int a = 0; a < 4; ++a) { sc[a][0] = 0.f; sc[a][1] = 0.f; }
    #pragma unroll 4
    for (int d = 0; d < 64; ++d) {
      float qv[4];
      *reinterpret_cast<float4*>(qv) =
          *reinterpret_cast<const float4*>(&Qt[d][wq * 4]);
      const float2 kv = *reinterpret_cast<const float2*>(&Kt[d][kx * 2]);
      #pragma unroll
      for (int a = 0; a < 4; ++a) {
        sc[a][0] = fmaf(qv[a], kv.x, sc[a][0]);
        sc[a][1] = fmaf(qv[a], kv.y, sc[a][1]);
      }
    }
    #pragma unroll
    for (int a = 0; a < 4; ++a) { sc[a][0] *= 0.125f; sc[a][1] *= 0.125f; }

    // row max over the 32 kx lanes
    float tm[4];
    #pragma unroll
    for (int a = 0; a < 4; ++a) tm[a] = fmaxf(sc[a][0], sc[a][1]);
    #pragma unroll
    for (int off = 1; off < 32; off <<= 1) {
      #pragma unroll
      for (int a = 0; a < 4; ++a) tm[a] = fmaxf(tm[a], __shfl_xor(tm[a], off));
    }

    // online update + exp
    float w0[4], w1[4];
    #pragma unroll
    for (int a = 0; a < 4; ++a) {
      const float mn = fmaxf(m[a], tm[a]);
      const float scale = __expf(m[a] - mn);
      m[a] = mn;
      lp[a] *= scale;
      o[a][0] *= scale;
      o[a][1] *= scale;
      w0[a] = __expf(sc[a][0] - mn);
      w1[a] = __expf(sc[a][1] - mn);
      lp[a] += w0[a] + w1[a];
    }
    *reinterpret_cast<float4*>(&Pt[kx * 2][wq * 4]) =
        make_float4(w0[0], w0[1], w0[2], w0[3]);
    *reinterpret_cast<float4*>(&Pt[kx * 2 + 1][wq * 4]) =
        make_float4(w1[0], w1[1], w1[2], w1[3]);
    __syncthreads();

    // PV
    #pragma unroll 4
    for (int k = 0; k < 64; ++k) {
      float pv[4];
      *reinterpret_cast<float4*>(pv) =
          *reinterpret_cast<const float4*>(&Pt[k][wq * 4]);
      const float2 vv = *reinterpret_cast<const float2*>(&Vs[k][kx * 2]);
      #pragma unroll
      for (int a = 0; a < 4; ++a) {
        o[a][0] = fmaf(pv[a], vv.x, o[a][0]);
        o[a][1] = fmaf(pv[a], vv.y, o[a][1]);
      }
    }
  }

  // total l across kx lanes
  #pragma unroll
  for (int off = 1; off < 32; off <<= 1) {
    #pragma unroll
    for (int a = 0; a < 4; ++a) lp[a] += __shfl_xor(lp[a], off);
  }

  #pragma unroll
  for (int a = 0; a < 4; ++a) {
    const int lq = g * 32 + wq * 4 + a;
    if (lq < NSEL) {
      const size_t row = ((size_t)b * NSEL + lq) * KS + kc;
      if (kx == 0) { Pm[row] = m[a]; Pl[row] = lp[a]; }
      *reinterpret_cast<float2*>(Po + row * 64 + kx * 2) =
          make_float2(o[a][0], o[a][1]);
    }
  }
}

// ---------------------------------------------------------------------------
// Kernel E: merge the KS partials per selected row; write final output.
// ---------------------------------------------------------------------------
__global__ __launch_bounds__(256) void combine_kernel(const int* __restrict__ Isel,
                                                      const float* __restrict__ Pm,
                                                      const float* __restrict__ Pl,
                                                      const float* __restrict__ Po,
                                                      float* __restrict__ out) {
  const int r = blockIdx.x * 4 + (threadIdx.x >> 6);
  if (r >= NB * NSEL) return;
  const int lane = threadIdx.x & 63;
  const int b = r / NSEL;
  const int qidx = Isel[r];
  const size_t base = (size_t)r * KS;

  float pm[KS];
  float gm = -3.0e38f;
  #pragma unroll
  for (int c = 0; c < KS; ++c) { pm[c] = Pm[base + c]; gm = fmaxf(gm, pm[c]); }
  float L = 0.f, od = 0.f;
  #pragma unroll
  for (int c = 0; c < KS; ++c) {
    const float e = __expf(pm[c] - gm);
    L += Pl[base + c] * e;
    od += Po[(base + c) * 64 + lane] * e;
  }
  out[((size_t)b * NN + qidx) * DH + lane] = od / L;
}

// ---------------------------------------------------------------------------
extern "C" void kernel_launch(void* const* d_in, const int* in_sizes, int n_in,
                              void* d_out, int out_size, void* d_ws, size_t ws_size,
                              hipStream_t stream) {
  const float* Q = (const float*)d_in[0];
  const float* K = (const float*)d_in[1];
  const float* V = (const float*)d_in[2];
  // d_in[3] (seed) unused: U == n -> full permutation; max/mean are
  // permutation-invariant, so M equals rowmax - rowmean of the full QK^T.
  float* out = (float*)d_out;

  float* Mmax = (float*)d_ws;                        // RS*NB*NN
  float* Msum = Mmax + (size_t)RS * NB * NN;         // RS*NB*NN
  int* Isel = (int*)(Msum + (size_t)RS * NB * NN);   // NB*NSEL
  float* Pm = (float*)(Isel + NB * NSEL);            // NB*NSEL*KS
  float* Pl = Pm + (size_t)NB * NSEL * KS;           // NB*NSEL*KS
  float* Po = Pl + (size_t)NB * NSEL * KS;           // NB*NSEL*KS*64

  rowstat_kernel<<<dim3(NN / 128, NB, RS), 256, 0, stream>>>(Q, K, Mmax, Msum);
  select_kernel<<<dim3(NB), 256, 0, stream>>>(Mmax, Msum, Isel);
  fill_kernel<<<dim3(NB * NN / 4), 256, 0, stream>>>(V, out);
  attn_part_kernel<<<dim3(8, KS, NB), 256, 0, stream>>>(Q, K, V, Isel, Pm, Pl, Po);
  combine_kernel<<<dim3((NB * NSEL + 3) / 4), 256, 0, stream>>>(Isel, Pm, Pl, Po, out);
}

// Round 6
// 242.050 us; speedup vs baseline: 1.2901x; 1.0509x over previous
//
#include <hip/hip_runtime.h>

#define NB 16
#define NN 2048
#define DH 64
#define NSEL 228     // int(30 * ln(2048))
#define KS 8         // attention key-split chunks
#define CHUNK (NN / KS)
#define RS 4         // rowstat key-split
#define EPSBAND 2.0e-3f  // >> worst-case bf16x3 score error (~7e-4)

using s16x8 = __attribute__((ext_vector_type(8))) short;
using f32x16 = __attribute__((ext_vector_type(16))) float;

static __device__ __forceinline__ unsigned short f2bf(float x) {
  unsigned int u = __float_as_uint(x);
  u += 0x7fffu + ((u >> 16) & 1u);  // RNE; fine for finite data
  return (unsigned short)(u >> 16);
}
static __device__ __forceinline__ float bf2f(unsigned short h) {
  return __uint_as_float(((unsigned int)h) << 16);
}
static __device__ __forceinline__ unsigned int enc(float f) {
  unsigned int u = __float_as_uint(f);
  return (u & 0x80000000u) ? ~u : (u | 0x80000000u);
}
static __device__ __forceinline__ float dec(unsigned int k) {
  return (k & 0x80000000u) ? __uint_as_float(k & 0x7fffffffu)
                           : __uint_as_float(~k);
}

// ---------------------------------------------------------------------------
// K -> bf16 hi/lo split (done once; rowstat re-reads it 16x via L3)
// ---------------------------------------------------------------------------
__global__ __launch_bounds__(256) void convk_kernel(const float* __restrict__ K,
                                                    unsigned short* __restrict__ Khi,
                                                    unsigned short* __restrict__ Klo) {
  const size_t e = ((size_t)blockIdx.x * 256 + threadIdx.x) * 8;
  float4 a = *(const float4*)(K + e);
  float4 b = *(const float4*)(K + e + 4);
  float v[8] = {a.x, a.y, a.z, a.w, b.x, b.y, b.z, b.w};
  union { unsigned short u[8]; s16x8 s; } H, L;
  #pragma unroll
  for (int j = 0; j < 8; ++j) {
    unsigned short h = f2bf(v[j]);
    H.u[j] = h;
    L.u[j] = f2bf(v[j] - bf2f(h));
  }
  *(s16x8*)(Khi + e) = H.s;
  *(s16x8*)(Klo + e) = L.s;
}

// ---------------------------------------------------------------------------
// Partial column sums of K (for the EXACT mean term: mean_i = q_i . Ksum / N)
// ---------------------------------------------------------------------------
__global__ __launch_bounds__(256) void kcolsum_kernel(const float* __restrict__ K,
                                                      float* __restrict__ Kpart) {
  __shared__ float part[4][64];
  const int b = blockIdx.y, ch = blockIdx.x;
  const int d = threadIdx.x & 63, g = threadIdx.x >> 6;
  const float* Kb = K + ((size_t)b * NN + ch * 128) * DH;
  float s = 0.f;
  for (int r = g; r < 128; r += 4) s += Kb[r * DH + d];
  part[g][d] = s;
  __syncthreads();
  if (threadIdx.x < 64)
    Kpart[((size_t)b * 16 + ch) * 64 + threadIdx.x] =
        part[0][threadIdx.x] + part[1][threadIdx.x] +
        part[2][threadIdx.x] + part[3][threadIdx.x];
}

// ---------------------------------------------------------------------------
// Kernel A (MFMA): rowmax of S = Q K^T over a 512-key chunk, bf16x3 split.
// Block: 4 waves x 32q = 128 q; K staged 128 rows/tile in LDS (hi+lo, 32 KB)
// with 16B XOR swizzle (chunk ^= row&7). Q frags register-resident.
// 3 MFMAs per kstep: qhi*khi + qhi*klo + qlo*khi (lo*lo dropped, <=~7e-4).
// Rowmax is invariant to C-row / K permutations, so only the verified
// col=lane&31 mapping matters; intra-lane k-mapping errors cancel (A and B
// use the same convention).
// ---------------------------------------------------------------------------
__global__ __launch_bounds__(256, 4) void rowstat_mfma(const float* __restrict__ Q,
                                                       const unsigned short* __restrict__ Khi,
                                                       const unsigned short* __restrict__ Klo,
                                                       float* __restrict__ Mmax) {
  __shared__ __align__(16) unsigned short KHs[128 * 64];
  __shared__ __align__(16) unsigned short KLs[128 * 64];
  const int b = blockIdx.y, cz = blockIdx.z;
  const int qbase = blockIdx.x * 128;
  const int tid = threadIdx.x;
  const int w = tid >> 6, lane = tid & 63;
  const int l31 = lane & 31, hi5 = lane >> 5;

  // Q fragments: lane holds Q[qbase+w*32+l31][kstep*16 + hi5*8 + 0..7]
  s16x8 qh[4], ql[4];
  {
    const float* qrow = Q + ((size_t)b * NN + qbase + w * 32 + l31) * DH;
    #pragma unroll
    for (int ks = 0; ks < 4; ++ks) {
      const int d0 = ks * 16 + hi5 * 8;
      float4 x = *(const float4*)(qrow + d0);
      float4 y = *(const float4*)(qrow + d0 + 4);
      float v[8] = {x.x, x.y, x.z, x.w, y.x, y.y, y.z, y.w};
      union { unsigned short u[8]; s16x8 s; } H, L;
      #pragma unroll
      for (int j = 0; j < 8; ++j) {
        unsigned short h = f2bf(v[j]);
        H.u[j] = h;
        L.u[j] = f2bf(v[j] - bf2f(h));
      }
      qh[ks] = H.s;
      ql[ks] = L.s;
    }
  }

  const size_t kbase = ((size_t)b * NN + cz * (NN / RS)) * DH;
  f32x16 vmax;
  #pragma unroll
  for (int i = 0; i < 16; ++i) vmax[i] = -3.0e38f;

  const int sr = tid >> 1;  // staging row
  const int sh = tid & 1;   // 32-elem column half

  for (int stage = 0; stage < NN / RS / 128; ++stage) {
    __syncthreads();
    {
      const size_t g = kbase + (size_t)(stage * 128 + sr) * DH + sh * 32;
      const unsigned short* gh = Khi + g;
      const unsigned short* gl = Klo + g;
      #pragma unroll
      for (int c = 0; c < 4; ++c) {
        s16x8 hv = *(const s16x8*)(gh + c * 8);
        s16x8 lv = *(const s16x8*)(gl + c * 8);
        const int chn = (sh * 4 + c) ^ (sr & 7);  // 16B-chunk XOR swizzle
        *(s16x8*)&KHs[(sr * 8 + chn) * 8] = hv;
        *(s16x8*)&KLs[(sr * 8 + chn) * 8] = lv;
      }
    }
    __syncthreads();

    #pragma unroll
    for (int ksub = 0; ksub < 4; ++ksub) {
      const int kr = ksub * 32 + l31;
      f32x16 acc;
      #pragma unroll
      for (int i = 0; i < 16; ++i) acc[i] = 0.f;
      #pragma unroll
      for (int ks = 0; ks < 4; ++ks) {
        const int chn = (ks * 2 + hi5) ^ (kr & 7);
        s16x8 ah = *(const s16x8*)&KHs[(kr * 8 + chn) * 8];
        s16x8 al = *(const s16x8*)&KLs[(kr * 8 + chn) * 8];
        acc = __builtin_amdgcn_mfma_f32_32x32x16_bf16(ah, qh[ks], acc, 0, 0, 0);
        acc = __builtin_amdgcn_mfma_f32_32x32x16_bf16(al, qh[ks], acc, 0, 0, 0);
        acc = __builtin_amdgcn_mfma_f32_32x32x16_bf16(ah, ql[ks], acc, 0, 0, 0);
      }
      #pragma unroll
      for (int i = 0; i < 16; ++i) vmax[i] = fmaxf(vmax[i], acc[i]);
    }
  }

  float m = vmax[0];
  #pragma unroll
  for (int i = 1; i < 16; ++i) m = fmaxf(m, vmax[i]);
  m = fmaxf(m, __shfl_xor(m, 32));
  if (lane < 32)
    Mmax[((size_t)cz * NB + b) * NN + qbase + w * 32 + lane] = m;
}

// ---------------------------------------------------------------------------
// Kernel B: exact mean + approx rowmax -> M~; radix top-228; fp32 recheck of
// rows within EPSBAND of the boundary; second radix; compaction
// (set semantics, ties index-ascending).
// ---------------------------------------------------------------------------
static __device__ unsigned int radix_thresh(const unsigned int* kreg, int lane,
                                            int wid, int* red) {
  unsigned int v = 0u;
  for (int bit = 31; bit >= 0; --bit) {
    const unsigned int cand = v | (1u << bit);
    int c = 0;
    #pragma unroll
    for (int f = 0; f < 8; ++f) c += (kreg[f] >= cand) ? 1 : 0;
    #pragma unroll
    for (int off = 1; off < 64; off <<= 1) c += __shfl_xor(c, off);
    if (lane == 0) red[wid] = c;
    __syncthreads();
    if (red[0] + red[1] + red[2] + red[3] >= NSEL) v = cand;
    __syncthreads();
  }
  return v;
}

__global__ __launch_bounds__(256) void select_kernel(const float* __restrict__ Q,
                                                     const float* __restrict__ K,
                                                     const float* __restrict__ Mmax,
                                                     const float* __restrict__ Kpart,
                                                     int* __restrict__ Isel) {
  __shared__ unsigned int keys[NN];
  __shared__ float meanv[NN];
  __shared__ int list_[NN];
  __shared__ float qsh[64];
  __shared__ float Ksl[64];
  __shared__ float fred[4];
  __shared__ int red[4];
  __shared__ int cntS;
  const int b = blockIdx.x;
  const int tid = threadIdx.x;
  const int lane = tid & 63, wid = tid >> 6;
  const int base = tid * 8;

  if (tid < 64) {
    float s = 0.f;
    for (int c = 0; c < 16; ++c) s += Kpart[((size_t)b * 16 + c) * 64 + tid];
    Ksl[tid] = s;
  }
  if (tid == 0) cntS = 0;
  __syncthreads();

  // phase 0: M~ = max(Mmax partials) - exact mean
  for (int f = 0; f < 8; ++f) {
    const int i = base + f;
    float mv = -3.0e38f;
    #pragma unroll
    for (int cz = 0; cz < RS; ++cz)
      mv = fmaxf(mv, Mmax[((size_t)cz * NB + b) * NN + i]);
    const float* qrow = Q + ((size_t)b * NN + i) * DH;
    float s = 0.f;
    #pragma unroll
    for (int d4 = 0; d4 < 16; ++d4) {
      float4 qv = *(const float4*)(qrow + d4 * 4);
      s = fmaf(qv.x, Ksl[d4 * 4 + 0], s);
      s = fmaf(qv.y, Ksl[d4 * 4 + 1], s);
      s = fmaf(qv.z, Ksl[d4 * 4 + 2], s);
      s = fmaf(qv.w, Ksl[d4 * 4 + 3], s);
    }
    const float mean = s * (1.0f / NN);
    meanv[i] = mean;
    keys[i] = enc(mv - mean);
  }
  __syncthreads();

  unsigned int kreg[8];
  #pragma unroll
  for (int f = 0; f < 8; ++f) kreg[f] = keys[base + f];

  // phase 1: approximate threshold
  const unsigned int v1 = radix_thresh(kreg, lane, wid, red);
  const float vf = dec(v1);

  // phase 2: collect boundary band, recompute exact fp32 rowmax for each
  #pragma unroll
  for (int f = 0; f < 8; ++f) {
    if (fabsf(dec(kreg[f]) - vf) <= EPSBAND) {
      int p = atomicAdd(&cntS, 1);
      list_[p] = base + f;
    }
  }
  __syncthreads();
  const int nband = cntS;
  for (int n = 0; n < nband; ++n) {
    const int row = list_[n];
    if (tid < 64) qsh[tid] = Q[((size_t)b * NN + row) * DH + tid];
    __syncthreads();
    float lmax = -3.0e38f;
    for (int j = tid; j < NN; j += 256) {
      const float* krow = K + ((size_t)b * NN + j) * DH;
      float s = 0.f;
      #pragma unroll
      for (int d4 = 0; d4 < 16; ++d4) {
        float4 kv = *(const float4*)(krow + d4 * 4);
        s = fmaf(kv.x, qsh[d4 * 4 + 0], s);
        s = fmaf(kv.y, qsh[d4 * 4 + 1], s);
        s = fmaf(kv.z, qsh[d4 * 4 + 2], s);
        s = fmaf(kv.w, qsh[d4 * 4 + 3], s);
      }
      lmax = fmaxf(lmax, s);
    }
    #pragma unroll
    for (int off = 1; off < 64; off <<= 1) lmax = fmaxf(lmax, __shfl_xor(lmax, off));
    if (lane == 0) fred[wid] = lmax;
    __syncthreads();
    if (tid == 0) {
      const float mx = fmaxf(fmaxf(fred[0], fred[1]), fmaxf(fred[2], fred[3]));
      keys[row] = enc(mx - meanv[row]);
    }
    __syncthreads();
  }
  #pragma unroll
  for (int f = 0; f < 8; ++f) kreg[f] = keys[base + f];

  // phase 3: exact threshold
  const unsigned int v2 = radix_thresh(kreg, lane, wid, red);

  // phase 4: compaction (strictly greater, then ==, index-ascending)
  int flg[8];
  int cnt = 0;
  #pragma unroll
  for (int f = 0; f < 8; ++f) { flg[f] = (kreg[f] > v2) ? 1 : 0; cnt += flg[f]; }
  int scan = cnt;
  #pragma unroll
  for (int off = 1; off < 64; off <<= 1) {
    const int t = __shfl_up(scan, off);
    if (lane >= off) scan += t;
  }
  if (lane == 63) red[wid] = scan;
  __syncthreads();
  int wbase = 0;
  for (int ww = 0; ww < wid; ++ww) wbase += red[ww];
  const int cg = red[0] + red[1] + red[2] + red[3];
  int pos = wbase + scan - cnt;
  #pragma unroll
  for (int f = 0; f < 8; ++f)
    if (flg[f]) { Isel[b * NSEL + pos] = base + f; ++pos; }
  __syncthreads();

  const int need = NSEL - cg;
  cnt = 0;
  #pragma unroll
  for (int f = 0; f < 8; ++f) { flg[f] = (kreg[f] == v2) ? 1 : 0; cnt += flg[f]; }
  scan = cnt;
  #pragma unroll
  for (int off = 1; off < 64; off <<= 1) {
    const int t = __shfl_up(scan, off);
    if (lane >= off) scan += t;
  }
  if (lane == 63) red[wid] = scan;
  __syncthreads();
  wbase = 0;
  for (int ww = 0; ww < wid; ++ww) wbase += red[ww];
  pos = wbase + scan - cnt;
  #pragma unroll
  for (int f = 0; f < 8; ++f)
    if (flg[f]) {
      if (pos < need) Isel[b * NSEL + cg + pos] = base + f;
      ++pos;
    }
}

// ---------------------------------------------------------------------------
// Kernel C: fill out[b][i][:] = mean_d V[b][i][:]
// ---------------------------------------------------------------------------
__global__ __launch_bounds__(256) void fill_kernel(const float* __restrict__ V,
                                                   float* __restrict__ out) {
  const size_t row = (size_t)blockIdx.x * 4 + (threadIdx.x >> 6);
  const int lane = threadIdx.x & 63;
  float x = V[row * DH + lane];
  #pragma unroll
  for (int off = 1; off < 64; off <<= 1) x += __shfl_xor(x, off);
  out[row * DH + lane] = x * (1.0f / DH);
}

// ---------------------------------------------------------------------------
// Kernel D: flash partials, register-tiled (unchanged from round 5).
// ---------------------------------------------------------------------------
__global__ __launch_bounds__(256) void attn_part_kernel(const float* __restrict__ Q,
                                                        const float* __restrict__ K,
                                                        const float* __restrict__ V,
                                                        const int* __restrict__ Isel,
                                                        float* __restrict__ Pm,
                                                        float* __restrict__ Pl,
                                                        float* __restrict__ Po) {
  __shared__ float Qt[64][32];
  __shared__ float Kt[64][64];
  __shared__ float Vs[64][64];
  __shared__ float Pt[64][36];
  const int b = blockIdx.z;
  const int kc = blockIdx.y;
  const int g = blockIdx.x;
  const int tid = threadIdx.x;
  const int wq = tid >> 5;
  const int kx = tid & 31;

  if (tid < 128) {
    const int rr = tid >> 2;
    const int dblk = (tid & 3) * 16;
    const int lq = g * 32 + rr;
    const int qidx = (lq < NSEL) ? Isel[b * NSEL + lq] : 0;
    const float* qs = Q + ((size_t)b * NN + qidx) * DH + dblk;
    #pragma unroll
    for (int f = 0; f < 4; ++f) {
      float4 v = *reinterpret_cast<const float4*>(qs + f * 4);
      Qt[dblk + f * 4 + 0][rr] = v.x;
      Qt[dblk + f * 4 + 1][rr] = v.y;
      Qt[dblk + f * 4 + 2][rr] = v.z;
      Qt[dblk + f * 4 + 3][rr] = v.w;
    }
  }

  const float* Kb = K + ((size_t)b * NN + kc * CHUNK) * DH;
  const float* Vb = V + ((size_t)b * NN + kc * CHUNK) * DH;

  float m[4], lp[4], o[4][2];
  #pragma unroll
  for (int a = 0; a < 4; ++a) {
    m[a] = -3.0e38f; lp[a] = 0.f; o[a][0] = 0.f; o[a][1] = 0.f;
  }

  for (int st = 0; st < CHUNK / 64; ++st) {
    __syncthreads();
    {
      const int rr = tid & 63;
      const int dblk = (tid >> 6) * 16;
      const float* ks = Kb + ((size_t)(st * 64 + rr)) * DH + dblk;
      #pragma unroll
      for (int f = 0; f < 4; ++f) {
        float4 v = *reinterpret_cast<const float4*>(ks + f * 4);
        Kt[dblk + f * 4 + 0][rr] = v.x;
        Kt[dblk + f * 4 + 1][rr] = v.y;
        Kt[dblk + f * 4 + 2][rr] = v.z;
        Kt[dblk + f * 4 + 3][rr] = v.w;
      }
      const float* vsrc = Vb + (size_t)st * 64 * DH;
      float* vdst = &Vs[0][0];
      #pragma unroll
      for (int it = 0; it < 4; ++it) {
        const int fo = (it * 256 + tid) * 4;
        *reinterpret_cast<float4*>(vdst + fo) =
            *reinterpret_cast<const float4*>(vsrc + fo);
      }
    }
    __syncthreads();

    float sc[4][2];
    #pragma unroll
    for (int a = 0; a < 4; ++a) { sc[a][0] = 0.f; sc[a][1] = 0.f; }
    #pragma unroll 4
    for (int d = 0; d < 64; ++d) {
      float qv[4];
      *reinterpret_cast<float4*>(qv) =
          *reinterpret_cast<const float4*>(&Qt[d][wq * 4]);
      const float2 kv = *reinterpret_cast<const float2*>(&Kt[d][kx * 2]);
      #pragma unroll
      for (int a = 0; a < 4; ++a) {
        sc[a][0] = fmaf(qv[a], kv.x, sc[a][0]);
        sc[a][1] = fmaf(qv[a], kv.y, sc[a][1]);
      }
    }
    #pragma unroll
    for (int a = 0; a < 4; ++a) { sc[a][0] *= 0.125f; sc[a][1] *= 0.125f; }

    float tm[4];
    #pragma unroll
    for (int a = 0; a < 4; ++a) tm[a] = fmaxf(sc[a][0], sc[a][1]);
    #pragma unroll
    for (int off = 1; off < 32; off <<= 1) {
      #pragma unroll
      for (int a = 0; a < 4; ++a) tm[a] = fmaxf(tm[a], __shfl_xor(tm[a], off));
    }

    float w0[4], w1[4];
    #pragma unroll
    for (int a = 0; a < 4; ++a) {
      const float mn = fmaxf(m[a], tm[a]);
      const float scale = __expf(m[a] - mn);
      m[a] = mn;
      lp[a] *= scale;
      o[a][0] *= scale;
      o[a][1] *= scale;
      w0[a] = __expf(sc[a][0] - mn);
      w1[a] = __expf(sc[a][1] - mn);
      lp[a] += w0[a] + w1[a];
    }
    *reinterpret_cast<float4*>(&Pt[kx * 2][wq * 4]) =
        make_float4(w0[0], w0[1], w0[2], w0[3]);
    *reinterpret_cast<float4*>(&Pt[kx * 2 + 1][wq * 4]) =
        make_float4(w1[0], w1[1], w1[2], w1[3]);
    __syncthreads();

    #pragma unroll 4
    for (int k = 0; k < 64; ++k) {
      float pv[4];
      *reinterpret_cast<float4*>(pv) =
          *reinterpret_cast<const float4*>(&Pt[k][wq * 4]);
      const float2 vv = *reinterpret_cast<const float2*>(&Vs[k][kx * 2]);
      #pragma unroll
      for (int a = 0; a < 4; ++a) {
        o[a][0] = fmaf(pv[a], vv.x, o[a][0]);
        o[a][1] = fmaf(pv[a], vv.y, o[a][1]);
      }
    }
  }

  #pragma unroll
  for (int off = 1; off < 32; off <<= 1) {
    #pragma unroll
    for (int a = 0; a < 4; ++a) lp[a] += __shfl_xor(lp[a], off);
  }

  #pragma unroll
  for (int a = 0; a < 4; ++a) {
    const int lq = g * 32 + wq * 4 + a;
    if (lq < NSEL) {
      const size_t row = ((size_t)b * NSEL + lq) * KS + kc;
      if (kx == 0) { Pm[row] = m[a]; Pl[row] = lp[a]; }
      *reinterpret_cast<float2*>(Po + row * 64 + kx * 2) =
          make_float2(o[a][0], o[a][1]);
    }
  }
}

// ---------------------------------------------------------------------------
// Kernel E: merge the KS partials per selected row; write final output.
// ---------------------------------------------------------------------------
__global__ __launch_bounds__(256) void combine_kernel(const int* __restrict__ Isel,
                                                      const float* __restrict__ Pm,
                                                      const float* __restrict__ Pl,
                                                      const float* __restrict__ Po,
                                                      float* __restrict__ out) {
  const int r = blockIdx.x * 4 + (threadIdx.x >> 6);
  if (r >= NB * NSEL) return;
  const int lane = threadIdx.x & 63;
  const int b = r / NSEL;
  const int qidx = Isel[r];
  const size_t base = (size_t)r * KS;

  float pm[KS];
  float gm = -3.0e38f;
  #pragma unroll
  for (int c = 0; c < KS; ++c) { pm[c] = Pm[base + c]; gm = fmaxf(gm, pm[c]); }
  float L = 0.f, od = 0.f;
  #pragma unroll
  for (int c = 0; c < KS; ++c) {
    const float e = __expf(pm[c] - gm);
    L += Pl[base + c] * e;
    od += Po[(base + c) * 64 + lane] * e;
  }
  out[((size_t)b * NN + qidx) * DH + lane] = od / L;
}

// ---------------------------------------------------------------------------
extern "C" void kernel_launch(void* const* d_in, const int* in_sizes, int n_in,
                              void* d_out, int out_size, void* d_ws, size_t ws_size,
                              hipStream_t stream) {
  const float* Q = (const float*)d_in[0];
  const float* K = (const float*)d_in[1];
  const float* V = (const float*)d_in[2];
  // d_in[3] (seed) unused: U == n -> full permutation; max/mean are
  // permutation-invariant, so M equals rowmax - rowmean of the full QK^T.
  float* out = (float*)d_out;

  float* Mmax = (float*)d_ws;                                  // RS*NB*NN
  float* Kpart = Mmax + (size_t)RS * NB * NN;                  // NB*16*64
  int* Isel = (int*)(Kpart + (size_t)NB * 16 * 64);            // NB*NSEL
  float* Pm = (float*)(Isel + NB * NSEL);                      // NB*NSEL*KS
  float* Pl = Pm + (size_t)NB * NSEL * KS;                     // NB*NSEL*KS
  float* Po = Pl + (size_t)NB * NSEL * KS;                     // NB*NSEL*KS*64
  unsigned short* Khi = (unsigned short*)(Po + (size_t)NB * NSEL * KS * 64);
  unsigned short* Klo = Khi + (size_t)NB * NN * DH;

  convk_kernel<<<dim3((NB * NN * DH) / (256 * 8)), 256, 0, stream>>>(K, Khi, Klo);
  kcolsum_kernel<<<dim3(16, NB), 256, 0, stream>>>(K, Kpart);
  rowstat_mfma<<<dim3(NN / 128, NB, RS), 256, 0, stream>>>(Q, Khi, Klo, Mmax);
  select_kernel<<<dim3(NB), 256, 0, stream>>>(Q, K, Mmax, Kpart, Isel);
  fill_kernel<<<dim3(NB * NN / 4), 256, 0, stream>>>(V, out);
  attn_part_kernel<<<dim3(8, KS, NB), 256, 0, stream>>>(Q, K, V, Isel, Pm, Pl, Po);
  combine_kernel<<<dim3((NB * NSEL + 3) / 4), 256, 0, stream>>>(Isel, Pm, Pl, Po, out);
}